// Round 11
// baseline (122.442 us; speedup 1.0000x reference)
//
#include <hip/hip_runtime.h>

// Problem constants
#define NTOK   2048
#define DIM    64
#define NCODES 50000
#define THRESH 100.0f
#define BIG    3.0e38f
#define MARGIN 5.0f      // screen err E <= 2|dd|(~2.5) + bf16(c2) err (~0.6); M >= 2E-ish w/ measured slack
#define NBLK   391       // 128-code MFMA blocks
#define BM32   1564      // 32-code screening blocks (391*4)
#define BM32P  1568      // bm32 row stride (slots >= BM32 never written/read)

typedef __attribute__((ext_vector_type(8)))  __bf16 bf16x8;
typedef __attribute__((ext_vector_type(16))) float  float16;

__device__ __forceinline__ unsigned short f2bf(float f) {
    union { float f; unsigned int u; } v; v.f = f;
    unsigned int r = v.u + 0x7FFF + ((v.u >> 16) & 1);
    return (unsigned short)(r >> 16);
}
__device__ __forceinline__ unsigned int pack2(float a, float b) {
    return (unsigned int)f2bf(a) | ((unsigned int)f2bf(b) << 16);
}

// ---------------------------------------------------------------------------
// Kernel 1 (prep): x only — fp32 -> bf16 (xbf) + x2 norms. 32 WGs.
// ---------------------------------------------------------------------------
__global__ __launch_bounds__(256)
void nn_prep_kernel(const float* __restrict__ x,
                    unsigned short* __restrict__ xbf,
                    float* __restrict__ x2) {
    int g = blockIdx.x * 256 + threadIdx.x;   // 0..8191
    int row = g >> 2;
    int seg = g & 3;
    const float* src = x + (size_t)row * DIM + seg * 16;
    unsigned short* dst = xbf + (size_t)row * DIM + seg * 16;
    float4 v0 = ((const float4*)src)[0];
    float4 v1 = ((const float4*)src)[1];
    float4 v2 = ((const float4*)src)[2];
    float4 v3 = ((const float4*)src)[3];
    float s = 0.f;
    s = fmaf(v0.x, v0.x, s); s = fmaf(v0.y, v0.y, s);
    s = fmaf(v0.z, v0.z, s); s = fmaf(v0.w, v0.w, s);
    s = fmaf(v1.x, v1.x, s); s = fmaf(v1.y, v1.y, s);
    s = fmaf(v1.z, v1.z, s); s = fmaf(v1.w, v1.w, s);
    s = fmaf(v2.x, v2.x, s); s = fmaf(v2.y, v2.y, s);
    s = fmaf(v2.z, v2.z, s); s = fmaf(v2.w, v2.w, s);
    s = fmaf(v3.x, v3.x, s); s = fmaf(v3.y, v3.y, s);
    s = fmaf(v3.z, v3.z, s); s = fmaf(v3.w, v3.w, s);
    uint4 lo, hi;
    lo.x = pack2(v0.x, v0.y); lo.y = pack2(v0.z, v0.w);
    lo.z = pack2(v1.x, v1.y); lo.w = pack2(v1.z, v1.w);
    hi.x = pack2(v2.x, v2.y); hi.y = pack2(v2.z, v2.w);
    hi.z = pack2(v3.x, v3.y); hi.w = pack2(v3.z, v3.w);
    *(uint4*)dst = lo;
    *(uint4*)(dst + 8) = hi;
    s += __shfl_xor(s, 1);
    s += __shfl_xor(s, 2);
    if (seg == 0) x2[row] = s;
}

// ---------------------------------------------------------------------------
// Kernel 2 (stage A): token-loop MFMA screening. ZERO LDS, zero barriers.
// Grid: (391 code blocks) x (2 token halves) = 782 WGs. Each wave owns all
// 4 mi groups (128 codes) of its block: A-fragments packed ONCE from fp32
// codes into registers; per iter (128 tokens/WG, 32/wave): B-frags stream
// from xbf (L2-resident, next-iter prefetch), 4 c2-init MFMAs (c2 folded in
// as a K=0 contribution: a_c2 x (-0.5)) + 16 K-step MFMAs, per-mi max
// epilogue -> one dwordx4 per wave-iter. bm32 = c2bf - 2*dot_bf.
// ---------------------------------------------------------------------------
__global__ __launch_bounds__(256, 2)
void nn_stageA_kernel(const unsigned short* __restrict__ xbf,
                      const float* __restrict__ codes,
                      float* __restrict__ bm32) {
    const int tid  = threadIdx.x;
    const int w    = tid >> 6;
    const int lane = tid & 63;
    const int l31  = lane & 31;
    const int h    = lane >> 5;
    const int blk  = blockIdx.x;          // 0..390
    const int n0   = blk * 128;
    const int tb0  = blockIdx.y * 1024;   // token half

    // ---- phase 0 (once): A fragments + bf16 c2 fragments ----
    bf16x8 afr[4][4];   // [mi][s]
    bf16x8 ac2[4];      // c2 at k=0 (h==0 lanes), else 0
#pragma unroll
    for (int mi = 0; mi < 4; ++mi) {
        int row = n0 + mi * 32 + l31;
        bool valid = row < NCODES;
        float s2 = 0.f;
#pragma unroll
        for (int s = 0; s < 4; ++s) {
            float4 a = make_float4(0.f, 0.f, 0.f, 0.f), b = a;
            if (valid) {
                const float4* p = (const float4*)(codes + (size_t)row * DIM + s * 16 + h * 8);
                a = p[0]; b = p[1];
            }
            s2 = fmaf(a.x, a.x, s2); s2 = fmaf(a.y, a.y, s2);
            s2 = fmaf(a.z, a.z, s2); s2 = fmaf(a.w, a.w, s2);
            s2 = fmaf(b.x, b.x, s2); s2 = fmaf(b.y, b.y, s2);
            s2 = fmaf(b.z, b.z, s2); s2 = fmaf(b.w, b.w, s2);
            uint4 pk;
            pk.x = pack2(a.x, a.y); pk.y = pack2(a.z, a.w);
            pk.z = pack2(b.x, b.y); pk.w = pack2(b.z, b.w);
            afr[mi][s] = *(bf16x8*)&pk;
        }
        s2 += __shfl_xor(s2, 32);          // both 32-dim halves
        float c2v = valid ? s2 : BIG;      // BIG -> -c2/2 ~ -1.6e38, never wins max
        uint4 uc = make_uint4(0u, 0u, 0u, 0u);
        if (h == 0) uc.x = (unsigned)f2bf(c2v);   // k=0 element
        ac2[mi] = *(bf16x8*)&uc;
    }
    uint4 ub = make_uint4(0u, 0u, 0u, 0u);
    if (h == 0) ub.x = 0xBF00u;            // bf16(-0.5), exact
    const bf16x8 bc2 = *(bf16x8*)&ub;
    float16 z16;
#pragma unroll
    for (int i = 0; i < 16; ++i) z16[i] = 0.f;

    // ---- token loop: 8 iters x 128 tokens (32 per wave) ----
    const unsigned short* xw = xbf + (size_t)(tb0 + w * 32 + l31) * DIM + h * 8;
    bf16x8 bcur[4], bnxt[4];
#pragma unroll
    for (int s = 0; s < 4; ++s) bcur[s] = *(const bf16x8*)(xw + s * 16);

#pragma unroll
    for (int t = 0; t < 8; ++t) {
        if (t < 7) {
            const unsigned short* xn = xw + (size_t)(t + 1) * 128 * DIM;
#pragma unroll
            for (int s = 0; s < 4; ++s) bnxt[s] = *(const bf16x8*)(xn + s * 16);
        }
        float16 acc[4];
        // init via MFMA: acc = a_c2 * (-0.5) + 0  ->  -c2bf/2 for every token
#pragma unroll
        for (int mi = 0; mi < 4; ++mi)
            acc[mi] = __builtin_amdgcn_mfma_f32_32x32x16_bf16(ac2[mi], bc2, z16, 0, 0, 0);
#pragma unroll
        for (int s = 0; s < 4; ++s)
#pragma unroll
            for (int mi = 0; mi < 4; ++mi)
                acc[mi] = __builtin_amdgcn_mfma_f32_32x32x16_bf16(
                    afr[mi][s], bcur[s], acc[mi], 0, 0, 0);

        // epilogue: per-token max(D) per mi; all 4 mi in-lane -> one dwordx4.
        // C/D: col = lane&31 (token), row = (r&3)+8*(r>>2)+4*h (code)
        float4 o;
#pragma unroll
        for (int mi = 0; mi < 4; ++mi) {
            float m = acc[mi][0];
#pragma unroll
            for (int r = 1; r < 16; ++r) m = fmaxf(m, acc[mi][r]);
            m = fmaxf(m, __shfl_xor(m, 32));   // merge h halves (rows +4)
            ((float*)&o)[mi] = -2.0f * m;
        }
        if (lane < 32) {
            int token = tb0 + t * 128 + w * 32 + l31;
            *(float4*)&bm32[(size_t)token * BM32P + blk * 4] = o;
        }
#pragma unroll
        for (int s = 0; s < 4; ++s) bcur[s] = bnxt[s];
    }
}

// ---------------------------------------------------------------------------
// Kernel 3 (finalize): one WG per token. Scan 1564 blockmins once, LDS-reduce
// gmin, LDS-enqueue candidate 32-blocks, waves round-robin exact-fp32
// rescore (2 lanes/code, 8 KB/cand). c2 recomputed inline (association
// verified absmax-0 on HW in the R8 run). No global atomics.
// ---------------------------------------------------------------------------
__global__ __launch_bounds__(256)
void nn_finalize_kernel(const float* __restrict__ x,
                        const float* __restrict__ codes,
                        const float* __restrict__ x2,
                        const float* __restrict__ bm32,
                        int* __restrict__ out) {
    __shared__ float redf[8];      // [0..3] wave gmin, [4..7] wave best-v
    __shared__ int   redi[4];
    __shared__ int   queue[BM32P];
    __shared__ int   qcount;
    __shared__ float gshare;

    const int tid  = threadIdx.x;
    const int w    = tid >> 6;
    const int lane = tid & 63;
    const int t    = blockIdx.x;
    const float* bm = bm32 + (size_t)t * BM32P;

    if (tid == 0) qcount = 0;

    float v[7];
    float g = BIG;
#pragma unroll
    for (int k = 0; k < 7; ++k) {
        int b = tid + k * 256;
        v[k] = (b < BM32) ? bm[b] : BIG;
        g = fminf(g, v[k]);
    }
#pragma unroll
    for (int m = 1; m < 64; m <<= 1) g = fminf(g, __shfl_xor(g, m));
    if (lane == 0) redf[w] = g;
    __syncthreads();
    if (tid == 0)
        gshare = fminf(fminf(redf[0], redf[1]), fminf(redf[2], redf[3])) + MARGIN;
    __syncthreads();
    const float th = gshare;

    // enqueue candidates (LDS atomic; order irrelevant — (v,id) total order)
#pragma unroll
    for (int k = 0; k < 7; ++k) {
        int b = tid + k * 256;
        if (b < BM32 && v[k] <= th) {
            int slot = atomicAdd(&qcount, 1);
            queue[slot] = b;
        }
    }
    __syncthreads();
    const int nq = qcount;

    // per-lane x half-row (half = lane&1 -> dims [0,32) or [32,64))
    const int half = lane & 1;
    float4 xh[8];
#pragma unroll
    for (int q = 0; q < 8; ++q)
        xh[q] = *(const float4*)(x + (size_t)t * DIM + half * 32 + q * 4);
    const float x2v = x2[t];

    float bv = BIG;
    int   bi = 0x7fffffff;
    for (int e = w; e < nq; e += 4) {
        int blk = queue[e];
        int n = blk * 32 + (lane >> 1);
        if (n < NCODES) {   // pair-uniform predicate
            const float4* cp = (const float4*)(codes + (size_t)n * DIM + half * 32);
            float4 c4[8];
#pragma unroll
            for (int q = 0; q < 8; ++q) c4[q] = cp[q];
            float d = 0.f;
#pragma unroll
            for (int q = 0; q < 8; ++q) {
                d = fmaf(xh[q].x, c4[q].x, d);
                d = fmaf(xh[q].y, c4[q].y, d);
                d = fmaf(xh[q].z, c4[q].z, d);
                d = fmaf(xh[q].w, c4[q].w, d);
            }
            d += __shfl_xor(d, 1);   // full 64-dim dot in both pair lanes
            // c2 inline: per-16-seg fmaf chains, (s0+s1)+(s2+s3)
            float sa = 0.f, sb = 0.f;
#pragma unroll
            for (int q = 0; q < 4; ++q) {
                sa = fmaf(c4[q].x, c4[q].x, sa); sa = fmaf(c4[q].y, c4[q].y, sa);
                sa = fmaf(c4[q].z, c4[q].z, sa); sa = fmaf(c4[q].w, c4[q].w, sa);
            }
#pragma unroll
            for (int q = 4; q < 8; ++q) {
                sb = fmaf(c4[q].x, c4[q].x, sb); sb = fmaf(c4[q].y, c4[q].y, sb);
                sb = fmaf(c4[q].z, c4[q].z, sb); sb = fmaf(c4[q].w, c4[q].w, sb);
            }
            float mysum = sa + sb;
            float other = __shfl_xor(mysum, 1);
            float c2v = half ? (other + mysum) : (mysum + other);
            float d2 = fmaxf(fmaf(-2.f, d, x2v + c2v), 0.f);
            if (d2 < bv || (d2 == bv && n < bi)) { bv = d2; bi = n; }
        }
    }
#pragma unroll
    for (int m = 1; m < 64; m <<= 1) {
        float vv = __shfl_xor(bv, m);
        int   ii = __shfl_xor(bi, m);
        if (vv < bv || (vv == bv && ii < bi)) { bv = vv; bi = ii; }
    }
    if (lane == 0) { redf[4 + w] = bv; redi[w] = bi; }
    __syncthreads();
    if (tid == 0) {
        float fb = BIG;
        int   fi = 0x7fffffff;
#pragma unroll
        for (int i = 0; i < 4; ++i) {
            float vv = redf[4 + i];
            int   ii = redi[i];
            if (vv < fb || (vv == fb && ii < fi)) { fb = vv; fi = ii; }
        }
        out[t] = (fb <= THRESH) ? fi : -1;
    }
}

// ---------------------------------------------------------------------------
// Workspace: x2[2048]f | xbf[2048*64]u16 | bm32[2048*1568]f   (~13.1 MB)
// ---------------------------------------------------------------------------
extern "C" void kernel_launch(void* const* d_in, const int* in_sizes, int n_in,
                              void* d_out, int out_size, void* d_ws, size_t ws_size,
                              hipStream_t stream) {
    const float* x     = (const float*)d_in[0];  // [2,1024,64]
    const float* codes = (const float*)d_in[1];  // [50000,64]

    float* x2 = (float*)d_ws;
    unsigned short* xbf = (unsigned short*)(x2 + NTOK);
    float* bm32 = (float*)(xbf + (size_t)NTOK * DIM);
    int* out = (int*)d_out;

    nn_prep_kernel<<<32, 256, 0, stream>>>(x, xbf, x2);
    nn_stageA_kernel<<<dim3(NBLK, 2), 256, 0, stream>>>(xbf, codes, bm32);
    nn_finalize_kernel<<<NTOK, 256, 0, stream>>>(x, codes, x2, bm32, out);
}